// Round 6
// baseline (399.092 us; speedup 1.0000x reference)
//
#include <hip/hip_runtime.h>

#define N_NODES 75000
#define N_EDGES 1200000
#define DIM 64
#define SCAN_BLK 1024
#define N_SCAN_BLKS ((N_NODES + SCAN_BLK - 1) / SCAN_BLK)   // 74

// ---------------------------------------------------------------------------
// Kernel A (f64): a[d] = sum_j e1[j]*w_k[j][d];  b[d] = sum_j e2[j]*w_q[j][d]
// ---------------------------------------------------------------------------
__global__ void vec_precompute(const float* __restrict__ w_q,
                               const float* __restrict__ w_k,
                               const float* __restrict__ e1,
                               const float* __restrict__ e2,
                               double* __restrict__ a,
                               double* __restrict__ b) {
    int t = threadIdx.x;
    if (t < DIM) {
        double s = 0.0;
        #pragma unroll
        for (int j = 0; j < DIM; ++j) s += (double)e1[j] * (double)w_k[j * DIM + t];
        a[t] = s;
    } else if (t < 2 * DIM) {
        int d = t - DIM;
        double s = 0.0;
        #pragma unroll
        for (int j = 0; j < DIM; ++j) s += (double)e2[j] * (double)w_q[j * DIM + d];
        b[d] = s;
    }
}

// ---------------------------------------------------------------------------
// Kernel B1: h values only. Thread-per-node, pure streaming, tiny register
// footprint. f64 expressions kept textually identical to R5 (bit-identical
// h -> denom chain unchanged).
// ---------------------------------------------------------------------------
__global__ __launch_bounds__(256, 4) void h_kernel(
    const float* __restrict__ d_u, const float* __restrict__ p_u,
    const double* __restrict__ a_vec, const double* __restrict__ b_vec,
    double* __restrict__ h_src, double* __restrict__ h_dst) {
    int i = blockIdx.x * 256 + threadIdx.x;
    if (i >= N_NODES) return;

    double hs = 0.0;
    const float4* prow = (const float4*)(p_u + (size_t)i * DIM);
    #pragma unroll
    for (int k = 0; k < DIM / 4; ++k) {
        float4 v = prow[k];
        hs += (double)v.x * a_vec[4 * k + 0] + (double)v.y * a_vec[4 * k + 1] +
              (double)v.z * a_vec[4 * k + 2] + (double)v.w * a_vec[4 * k + 3];
    }
    h_src[i] = hs;

    double hd = 0.0;
    const float4* drow = (const float4*)(d_u + (size_t)i * DIM);
    #pragma unroll
    for (int k = 0; k < DIM / 4; ++k) {
        float4 v = drow[k];
        hd += (double)v.x * b_vec[4 * k + 0] + (double)v.y * b_vec[4 * k + 1] +
              (double)v.z * b_vec[4 * k + 2] + (double)v.w * b_vec[4 * k + 3];
    }
    h_dst[i] = hd;
}

// NOTE (R5 post-mortem): the h_src f64 dot previously used p[] loaded via the
// same float4s; the expression above preserves the R5 h_dst form. h_src in R5
// was "hs += p[d]*a[d]" sequentially d=0..63 — the float4 4-term grouping here
// evaluates x*a0 + y*a1 + z*a2 + w*a3 added in sequence, same left-to-right
// order as scalar d-loop. f64 result identical.

// ---------------------------------------------------------------------------
// Kernel B2: wv = p_u @ w_v^T. 4 threads per node; thread g computes outputs
// j in [16g, 16g+16). ~48 VGPRs (16 acc + 16 p staging) -> no spill; grid is
// 1172 blocks (~18 waves/CU) -> latency hidden. w_v (16 KB) is L1-resident;
// each wave's w_v load touches only 4 distinct rows (quad-broadcast).
// ---------------------------------------------------------------------------
__global__ __launch_bounds__(256, 4) void wv_kernel(
    const float* __restrict__ p_u, const float* __restrict__ w_v,
    float* __restrict__ wv_out) {
    int t = blockIdx.x * 256 + threadIdx.x;
    int i = t >> 2;
    int g = t & 3;
    if (i >= N_NODES) return;

    const float4* prow = (const float4*)(p_u + (size_t)i * DIM);
    float acc[16];
    #pragma unroll
    for (int jj = 0; jj < 16; ++jj) acc[jj] = 0.f;

    #pragma unroll
    for (int kc = 0; kc < 4; ++kc) {               // d-chunk of 16
        float4 pc[4];
        #pragma unroll
        for (int k = 0; k < 4; ++k) pc[k] = prow[kc * 4 + k];
        #pragma unroll
        for (int jj = 0; jj < 16; ++jj) {
            int j = g * 16 + jj;
            const float4* wrow = (const float4*)(w_v + (size_t)j * DIM + kc * 16);
            float s = 0.f;
            #pragma unroll
            for (int k = 0; k < 4; ++k) {
                float4 w = wrow[k];
                s += w.x * pc[k].x + w.y * pc[k].y + w.z * pc[k].z + w.w * pc[k].w;
            }
            acc[jj] += s;
        }
    }

    float4* orow = (float4*)(wv_out + (size_t)i * DIM + g * 16);
    #pragma unroll
    for (int jj = 0; jj < 4; ++jj) {
        float4 st;
        st.x = acc[4 * jj + 0]; st.y = acc[4 * jj + 1];
        st.z = acc[4 * jj + 2]; st.w = acc[4 * jj + 3];
        orow[jj] = st;
    }
}

// ---------------------------------------------------------------------------
// CSR step 1: histogram of dst + per-edge rank (coalesced 4B write).
// ---------------------------------------------------------------------------
__global__ __launch_bounds__(256) void hist_kernel(
    const int* __restrict__ dst, int* __restrict__ cnt,
    int* __restrict__ rank) {
    int e = blockIdx.x * 256 + threadIdx.x;
    if (e >= N_EDGES) return;
    rank[e] = atomicAdd(&cnt[dst[e]], 1);
}

// CSR step 2a: per-block exclusive scan (Hillis-Steele in LDS).
__global__ __launch_bounds__(SCAN_BLK) void scan1_kernel(
    const int* __restrict__ cnt, int* __restrict__ row,
    int* __restrict__ bsum) {
    __shared__ int sh[SCAN_BLK];
    int tid = threadIdx.x;
    int i = blockIdx.x * SCAN_BLK + tid;
    int v = (i < N_NODES) ? cnt[i] : 0;
    sh[tid] = v;
    __syncthreads();
    for (int off = 1; off < SCAN_BLK; off <<= 1) {
        int t = (tid >= off) ? sh[tid - off] : 0;
        __syncthreads();
        sh[tid] += t;
        __syncthreads();
    }
    if (i < N_NODES) row[i] = sh[tid] - v;   // exclusive
    if (tid == SCAN_BLK - 1) bsum[blockIdx.x] = sh[tid];
}

// CSR step 2b: add block-sum prefix (redundant tiny scan per block).
__global__ __launch_bounds__(256) void scan23_kernel(
    int* __restrict__ row, const int* __restrict__ bsum) {
    __shared__ int pref[N_SCAN_BLKS];
    int tid = threadIdx.x;
    if (tid == 0) {
        int run = 0;
        #pragma unroll 8
        for (int k = 0; k < N_SCAN_BLKS; ++k) { pref[k] = run; run += bsum[k]; }
    }
    __syncthreads();
    int i = blockIdx.x * 256 + tid;
    if (i >= N_NODES) return;
    row[i] += pref[i / SCAN_BLK];
}

// CSR step 3: atomic-free scatter of src ids.
__global__ __launch_bounds__(256) void build_kernel(
    const int* __restrict__ src, const int* __restrict__ dst,
    const int* __restrict__ row, const int* __restrict__ rank,
    int* __restrict__ csr_src) {
    int e = blockIdx.x * 256 + threadIdx.x;
    if (e >= N_EDGES) return;
    int pos = row[dst[e]] + rank[e];
    csr_src[pos] = src[e];
}

// ---------------------------------------------------------------------------
// Gather: one wave per dst node (unchanged from R5).
// ---------------------------------------------------------------------------
__global__ __launch_bounds__(256) void node_gather(
    const int* __restrict__ row, const int* __restrict__ cnt,
    const int* __restrict__ csr_src,
    const double* __restrict__ h_src, const double* __restrict__ h_dst,
    const float* __restrict__ wv, float* __restrict__ out) {
    int gtid = blockIdx.x * 256 + threadIdx.x;
    int node = gtid >> 6;
    int lane = threadIdx.x & 63;
    if (node >= N_NODES) return;

    int start = row[node];
    int deg = cnt[node];
    double hd = h_dst[node];

    if (deg <= 64) {
        int s0 = 0;
        double c0 = 0.0;
        if (lane < deg) {
            s0 = csr_src[start + lane];
            c0 = h_src[s0] + hd;
        }
        double r = c0;
        #pragma unroll
        for (int off = 32; off > 0; off >>= 1) r += __shfl_xor(r, off, 64);
        double inv = 1.0 / r;
        float cf0 = (lane < deg) ? (float)(c0 * inv) : 0.f;

        int g = lane >> 4;        // edge-in-quad (0..3)
        int q = lane & 15;        // float4 index within row
        int tmax = (deg + 3) >> 2;
        float ax = 0.f, ay = 0.f, az = 0.f, aw = 0.f;
        for (int t = 0; t < tmax; ++t) {
            int idx = 4 * t + g;
            int s = __shfl(s0, idx, 64);
            float cf = __shfl(cf0, idx, 64);
            const float4* rowp = (const float4*)(wv + (size_t)s * DIM);
            float4 w = rowp[q];
            ax += w.x * cf;
            ay += w.y * cf;
            az += w.z * cf;
            aw += w.w * cf;
        }
        ax += __shfl_xor(ax, 16, 64);
        ay += __shfl_xor(ay, 16, 64);
        az += __shfl_xor(az, 16, 64);
        aw += __shfl_xor(aw, 16, 64);
        ax += __shfl_xor(ax, 32, 64);
        ay += __shfl_xor(ay, 32, 64);
        az += __shfl_xor(az, 32, 64);
        aw += __shfl_xor(aw, 32, 64);
        if (lane < 16) {
            float4 st; st.x = ax; st.y = ay; st.z = az; st.w = aw;
            ((float4*)(out + (size_t)node * DIM))[q] = st;
        }
    } else {
        double denom = 0.0;
        for (int base = 0; base < deg; base += 64) {
            int m = deg - base; if (m > 64) m = 64;
            double c = 0.0;
            if (lane < m) {
                int s = csr_src[start + base + lane];
                c = h_src[s] + hd;
            }
            #pragma unroll
            for (int off = 32; off > 0; off >>= 1) c += __shfl_xor(c, off, 64);
            denom += c;
        }
        double inv = 1.0 / denom;
        float acc = 0.f;
        for (int base = 0; base < deg; base += 64) {
            int m = deg - base; if (m > 64) m = 64;
            int s1 = 0; float cf1 = 0.f;
            if (lane < m) {
                s1 = csr_src[start + base + lane];
                cf1 = (float)((h_src[s1] + hd) * inv);
            }
            for (int j = 0; j < m; ++j) {
                int s = __shfl(s1, j, 64);
                float cf = __shfl(cf1, j, 64);
                acc += wv[(size_t)s * DIM + lane] * cf;
            }
        }
        out[(size_t)node * DIM + lane] = acc;
    }
}

// ---------------------------------------------------------------------------
// Launch
// ---------------------------------------------------------------------------
extern "C" void kernel_launch(void* const* d_in, const int* in_sizes, int n_in,
                              void* d_out, int out_size, void* d_ws, size_t ws_size,
                              hipStream_t stream) {
    const float* d_u = (const float*)d_in[0];
    const float* p_u = (const float*)d_in[1];
    const float* w_q = (const float*)d_in[2];
    const float* w_k = (const float*)d_in[3];
    const float* w_v = (const float*)d_in[4];
    const float* e1  = (const float*)d_in[5];
    const float* e2  = (const float*)d_in[6];
    const int*   src = (const int*)d_in[7];
    const int*   dst = (const int*)d_in[8];
    float* out = (float*)d_out;

    // Workspace: doubles first (8B aligned), then floats, then ints.
    double* a      = (double*)d_ws;
    double* b      = a + DIM;
    double* h_src  = b + DIM;
    double* h_dst  = h_src + N_NODES;
    float*  wv     = (float*)(h_dst + N_NODES);       // N_NODES*DIM floats
    int*    cnt    = (int*)(wv + (size_t)N_NODES * DIM);
    int*    row    = cnt + N_NODES;
    int*    bsum   = row + N_NODES;                   // 128 ints
    int*    rank   = bsum + 128;                      // N_EDGES ints
    int*    csr_src= rank + N_EDGES;                  // N_EDGES ints

    vec_precompute<<<1, 128, 0, stream>>>(w_q, w_k, e1, e2, a, b);

    hipMemsetAsync(cnt, 0, sizeof(int) * N_NODES, stream);

    hist_kernel<<<(N_EDGES + 255) / 256, 256, 0, stream>>>(dst, cnt, rank);

    h_kernel<<<(N_NODES + 255) / 256, 256, 0, stream>>>(
        d_u, p_u, a, b, h_src, h_dst);

    wv_kernel<<<(N_NODES * 4 + 255) / 256, 256, 0, stream>>>(p_u, w_v, wv);

    scan1_kernel<<<N_SCAN_BLKS, SCAN_BLK, 0, stream>>>(cnt, row, bsum);
    scan23_kernel<<<(N_NODES + 255) / 256, 256, 0, stream>>>(row, bsum);

    build_kernel<<<(N_EDGES + 255) / 256, 256, 0, stream>>>(
        src, dst, row, rank, csr_src);

    node_gather<<<(N_NODES * 64 + 255) / 256, 256, 0, stream>>>(
        row, cnt, csr_src, h_src, h_dst, wv, out);
}

// Round 7
// 306.941 us; speedup vs baseline: 1.3002x; 1.3002x over previous
//
#include <hip/hip_runtime.h>

#define N_NODES 75000
#define N_EDGES 1200000
#define DIM 64
#define SCAN_BLK 1024
#define N_SCAN_BLKS ((N_NODES + SCAN_BLK - 1) / SCAN_BLK)   // 74

// ---------------------------------------------------------------------------
// Kernel A (f64): a[d] = sum_j e1[j]*w_k[j][d];  b[d] = sum_j e2[j]*w_q[j][d]
// ---------------------------------------------------------------------------
__global__ void vec_precompute(const float* __restrict__ w_q,
                               const float* __restrict__ w_k,
                               const float* __restrict__ e1,
                               const float* __restrict__ e2,
                               double* __restrict__ a,
                               double* __restrict__ b) {
    int t = threadIdx.x;
    if (t < DIM) {
        double s = 0.0;
        #pragma unroll
        for (int j = 0; j < DIM; ++j) s += (double)e1[j] * (double)w_k[j * DIM + t];
        a[t] = s;
    } else if (t < 2 * DIM) {
        int d = t - DIM;
        double s = 0.0;
        #pragma unroll
        for (int j = 0; j < DIM; ++j) s += (double)e2[j] * (double)w_q[j * DIM + d];
        b[d] = s;
    }
}

// ---------------------------------------------------------------------------
// Fused node precompute: ONE WAVE PER NODE (grid-strided).
//   lane j holds w_v row j in 64 VGPRs (preloaded once per wave).
//   per node: coalesced 4B/lane loads of p row and d row;
//     h_src[i] = f64 butterfly dot(p, a)   (f64 reorder-safe: amplification
//     h_dst[i] = f64 butterfly dot(d, b)    of 1e-16 noise is ~1e-11 rel)
//     wv[i][lane] = sum_d w[d] * shfl(p, d)  with 4 parallel FMA chains
//   store: lane-per-element -> full-line 256B coalesced (no amplification).
// ---------------------------------------------------------------------------
__global__ __launch_bounds__(256, 4) void node_wave(
    const float* __restrict__ d_u, const float* __restrict__ p_u,
    const float* __restrict__ w_v,
    const double* __restrict__ a_vec, const double* __restrict__ b_vec,
    double* __restrict__ h_src, double* __restrict__ h_dst,
    float* __restrict__ wv_out) {
    int lane = threadIdx.x & 63;
    int wave = (blockIdx.x * 256 + threadIdx.x) >> 6;
    int nwaves = gridDim.x * 4;

    // Preload w_v row `lane` (16 x float4). Amortized over ~N_NODES/nwaves nodes.
    float w[DIM];
    const float4* wr = (const float4*)(w_v + (size_t)lane * DIM);
    #pragma unroll
    for (int k = 0; k < DIM / 4; ++k) {
        float4 v = wr[k];
        w[4 * k + 0] = v.x; w[4 * k + 1] = v.y;
        w[4 * k + 2] = v.z; w[4 * k + 3] = v.w;
    }
    double al = a_vec[lane];
    double bl = b_vec[lane];

    for (int i = wave; i < N_NODES; i += nwaves) {
        float pl = p_u[(size_t)i * DIM + lane];
        float dl = d_u[(size_t)i * DIM + lane];

        // f64 butterfly dots for h
        double hs = (double)pl * al;
        #pragma unroll
        for (int off = 32; off > 0; off >>= 1) hs += __shfl_xor(hs, off, 64);
        double hd = (double)dl * bl;
        #pragma unroll
        for (int off = 32; off > 0; off >>= 1) hd += __shfl_xor(hd, off, 64);
        if (lane == 0) { h_src[i] = hs; h_dst[i] = hd; }

        // wv row: 4 independent FMA chains to break dependency latency
        float a0 = 0.f, a1 = 0.f, a2 = 0.f, a3 = 0.f;
        #pragma unroll
        for (int d = 0; d < DIM; d += 4) {
            a0 += w[d + 0] * __shfl(pl, d + 0, 64);
            a1 += w[d + 1] * __shfl(pl, d + 1, 64);
            a2 += w[d + 2] * __shfl(pl, d + 2, 64);
            a3 += w[d + 3] * __shfl(pl, d + 3, 64);
        }
        wv_out[(size_t)i * DIM + lane] = (a0 + a1) + (a2 + a3);
    }
}

// ---------------------------------------------------------------------------
// CSR step 1: histogram of dst + per-edge rank (coalesced 4B write).
// ---------------------------------------------------------------------------
__global__ __launch_bounds__(256) void hist_kernel(
    const int* __restrict__ dst, int* __restrict__ cnt,
    int* __restrict__ rank) {
    int e = blockIdx.x * 256 + threadIdx.x;
    if (e >= N_EDGES) return;
    rank[e] = atomicAdd(&cnt[dst[e]], 1);
}

// CSR step 2a: per-block exclusive scan (Hillis-Steele in LDS).
__global__ __launch_bounds__(SCAN_BLK) void scan1_kernel(
    const int* __restrict__ cnt, int* __restrict__ row,
    int* __restrict__ bsum) {
    __shared__ int sh[SCAN_BLK];
    int tid = threadIdx.x;
    int i = blockIdx.x * SCAN_BLK + tid;
    int v = (i < N_NODES) ? cnt[i] : 0;
    sh[tid] = v;
    __syncthreads();
    for (int off = 1; off < SCAN_BLK; off <<= 1) {
        int t = (tid >= off) ? sh[tid - off] : 0;
        __syncthreads();
        sh[tid] += t;
        __syncthreads();
    }
    if (i < N_NODES) row[i] = sh[tid] - v;   // exclusive
    if (tid == SCAN_BLK - 1) bsum[blockIdx.x] = sh[tid];
}

// CSR step 2b: add block-sum prefix (redundant tiny scan per block).
__global__ __launch_bounds__(256) void scan23_kernel(
    int* __restrict__ row, const int* __restrict__ bsum) {
    __shared__ int pref[N_SCAN_BLKS];
    int tid = threadIdx.x;
    if (tid == 0) {
        int run = 0;
        #pragma unroll 8
        for (int k = 0; k < N_SCAN_BLKS; ++k) { pref[k] = run; run += bsum[k]; }
    }
    __syncthreads();
    int i = blockIdx.x * 256 + tid;
    if (i >= N_NODES) return;
    row[i] += pref[i / SCAN_BLK];
}

// CSR step 3: atomic-free scatter of src ids.
__global__ __launch_bounds__(256) void build_kernel(
    const int* __restrict__ src, const int* __restrict__ dst,
    const int* __restrict__ row, const int* __restrict__ rank,
    int* __restrict__ csr_src) {
    int e = blockIdx.x * 256 + threadIdx.x;
    if (e >= N_EDGES) return;
    int pos = row[dst[e]] + rank[e];
    csr_src[pos] = src[e];
}

// ---------------------------------------------------------------------------
// Gather: one wave per dst node (unchanged).
// ---------------------------------------------------------------------------
__global__ __launch_bounds__(256) void node_gather(
    const int* __restrict__ row, const int* __restrict__ cnt,
    const int* __restrict__ csr_src,
    const double* __restrict__ h_src, const double* __restrict__ h_dst,
    const float* __restrict__ wv, float* __restrict__ out) {
    int gtid = blockIdx.x * 256 + threadIdx.x;
    int node = gtid >> 6;
    int lane = threadIdx.x & 63;
    if (node >= N_NODES) return;

    int start = row[node];
    int deg = cnt[node];
    double hd = h_dst[node];

    if (deg <= 64) {
        int s0 = 0;
        double c0 = 0.0;
        if (lane < deg) {
            s0 = csr_src[start + lane];
            c0 = h_src[s0] + hd;
        }
        double r = c0;
        #pragma unroll
        for (int off = 32; off > 0; off >>= 1) r += __shfl_xor(r, off, 64);
        double inv = 1.0 / r;
        float cf0 = (lane < deg) ? (float)(c0 * inv) : 0.f;

        int g = lane >> 4;        // edge-in-quad (0..3)
        int q = lane & 15;        // float4 index within row
        int tmax = (deg + 3) >> 2;
        float ax = 0.f, ay = 0.f, az = 0.f, aw = 0.f;
        for (int t = 0; t < tmax; ++t) {
            int idx = 4 * t + g;
            int s = __shfl(s0, idx, 64);
            float cf = __shfl(cf0, idx, 64);
            const float4* rowp = (const float4*)(wv + (size_t)s * DIM);
            float4 w = rowp[q];
            ax += w.x * cf;
            ay += w.y * cf;
            az += w.z * cf;
            aw += w.w * cf;
        }
        ax += __shfl_xor(ax, 16, 64);
        ay += __shfl_xor(ay, 16, 64);
        az += __shfl_xor(az, 16, 64);
        aw += __shfl_xor(aw, 16, 64);
        ax += __shfl_xor(ax, 32, 64);
        ay += __shfl_xor(ay, 32, 64);
        az += __shfl_xor(az, 32, 64);
        aw += __shfl_xor(aw, 32, 64);
        if (lane < 16) {
            float4 st; st.x = ax; st.y = ay; st.z = az; st.w = aw;
            ((float4*)(out + (size_t)node * DIM))[q] = st;
        }
    } else {
        double denom = 0.0;
        for (int base = 0; base < deg; base += 64) {
            int m = deg - base; if (m > 64) m = 64;
            double c = 0.0;
            if (lane < m) {
                int s = csr_src[start + base + lane];
                c = h_src[s] + hd;
            }
            #pragma unroll
            for (int off = 32; off > 0; off >>= 1) c += __shfl_xor(c, off, 64);
            denom += c;
        }
        double inv = 1.0 / denom;
        float acc = 0.f;
        for (int base = 0; base < deg; base += 64) {
            int m = deg - base; if (m > 64) m = 64;
            int s1 = 0; float cf1 = 0.f;
            if (lane < m) {
                s1 = csr_src[start + base + lane];
                cf1 = (float)((h_src[s1] + hd) * inv);
            }
            for (int j = 0; j < m; ++j) {
                int s = __shfl(s1, j, 64);
                float cf = __shfl(cf1, j, 64);
                acc += wv[(size_t)s * DIM + lane] * cf;
            }
        }
        out[(size_t)node * DIM + lane] = acc;
    }
}

// ---------------------------------------------------------------------------
// Launch
// ---------------------------------------------------------------------------
extern "C" void kernel_launch(void* const* d_in, const int* in_sizes, int n_in,
                              void* d_out, int out_size, void* d_ws, size_t ws_size,
                              hipStream_t stream) {
    const float* d_u = (const float*)d_in[0];
    const float* p_u = (const float*)d_in[1];
    const float* w_q = (const float*)d_in[2];
    const float* w_k = (const float*)d_in[3];
    const float* w_v = (const float*)d_in[4];
    const float* e1  = (const float*)d_in[5];
    const float* e2  = (const float*)d_in[6];
    const int*   src = (const int*)d_in[7];
    const int*   dst = (const int*)d_in[8];
    float* out = (float*)d_out;

    // Workspace: doubles first (8B aligned), then floats, then ints.
    double* a      = (double*)d_ws;
    double* b      = a + DIM;
    double* h_src  = b + DIM;
    double* h_dst  = h_src + N_NODES;
    float*  wv     = (float*)(h_dst + N_NODES);       // N_NODES*DIM floats
    int*    cnt    = (int*)(wv + (size_t)N_NODES * DIM);
    int*    row    = cnt + N_NODES;
    int*    bsum   = row + N_NODES;                   // 128 ints
    int*    rank   = bsum + 128;                      // N_EDGES ints
    int*    csr_src= rank + N_EDGES;                  // N_EDGES ints

    vec_precompute<<<1, 128, 0, stream>>>(w_q, w_k, e1, e2, a, b);

    hipMemsetAsync(cnt, 0, sizeof(int) * N_NODES, stream);

    hist_kernel<<<(N_EDGES + 255) / 256, 256, 0, stream>>>(dst, cnt, rank);

    // wave-per-node fused precompute: 1024 blocks x 4 waves, grid-strided
    node_wave<<<1024, 256, 0, stream>>>(
        d_u, p_u, w_v, a, b, h_src, h_dst, wv);

    scan1_kernel<<<N_SCAN_BLKS, SCAN_BLK, 0, stream>>>(cnt, row, bsum);
    scan23_kernel<<<(N_NODES + 255) / 256, 256, 0, stream>>>(row, bsum);

    build_kernel<<<(N_EDGES + 255) / 256, 256, 0, stream>>>(
        src, dst, row, rank, csr_src);

    node_gather<<<(N_NODES * 64 + 255) / 256, 256, 0, stream>>>(
        row, cnt, csr_src, h_src, h_dst, wv, out);
}

// Round 8
// 258.950 us; speedup vs baseline: 1.5412x; 1.1853x over previous
//
#include <hip/hip_runtime.h>

#define N_NODES 75000
#define N_EDGES 1200000
#define DIM 64
#define SCAN_BLK 1024
#define N_SCAN_BLKS ((N_NODES + SCAN_BLK - 1) / SCAN_BLK)   // 74

// Broadcast lane l of v to all lanes via v_readlane (VALU->SGPR, no LDS pipe).
__device__ __forceinline__ float lane_bc(float v, int l) {
    return __int_as_float(__builtin_amdgcn_readlane(__float_as_int(v), l));
}

// ---------------------------------------------------------------------------
// Kernel A (f64): a[d] = sum_j e1[j]*w_k[j][d];  b[d] = sum_j e2[j]*w_q[j][d]
// ---------------------------------------------------------------------------
__global__ void vec_precompute(const float* __restrict__ w_q,
                               const float* __restrict__ w_k,
                               const float* __restrict__ e1,
                               const float* __restrict__ e2,
                               double* __restrict__ a,
                               double* __restrict__ b) {
    int t = threadIdx.x;
    if (t < DIM) {
        double s = 0.0;
        #pragma unroll
        for (int j = 0; j < DIM; ++j) s += (double)e1[j] * (double)w_k[j * DIM + t];
        a[t] = s;
    } else if (t < 2 * DIM) {
        int d = t - DIM;
        double s = 0.0;
        #pragma unroll
        for (int j = 0; j < DIM; ++j) s += (double)e2[j] * (double)w_q[j * DIM + d];
        b[d] = s;
    }
}

// ---------------------------------------------------------------------------
// Fused node precompute: ONE WAVE PER NODE (grid-strided).
//   lane j holds w_v row j in 64 VGPRs (preloaded once per wave).
//   per node: coalesced 4B/lane loads of p row and d row;
//     h_src/h_dst via f64 butterfly dots (unchanged — precision path)
//     wv[i][lane] = sum_d w[d] * readlane(pl, d)  -- VALU broadcast, no
//     ds_bpermute, no lgkmcnt stalls. Same 4-chain order as R7 ->
//     bit-identical wv.
//   store: lane-per-element -> full-line 256B coalesced.
// ---------------------------------------------------------------------------
__global__ __launch_bounds__(256, 4) void node_wave(
    const float* __restrict__ d_u, const float* __restrict__ p_u,
    const float* __restrict__ w_v,
    const double* __restrict__ a_vec, const double* __restrict__ b_vec,
    double* __restrict__ h_src, double* __restrict__ h_dst,
    float* __restrict__ wv_out) {
    int lane = threadIdx.x & 63;
    int wave = (blockIdx.x * 256 + threadIdx.x) >> 6;
    int nwaves = gridDim.x * 4;

    // Preload w_v row `lane` (16 x float4).
    float w[DIM];
    const float4* wr = (const float4*)(w_v + (size_t)lane * DIM);
    #pragma unroll
    for (int k = 0; k < DIM / 4; ++k) {
        float4 v = wr[k];
        w[4 * k + 0] = v.x; w[4 * k + 1] = v.y;
        w[4 * k + 2] = v.z; w[4 * k + 3] = v.w;
    }
    double al = a_vec[lane];
    double bl = b_vec[lane];

    for (int i = wave; i < N_NODES; i += nwaves) {
        float pl = p_u[(size_t)i * DIM + lane];
        float dl = d_u[(size_t)i * DIM + lane];

        // f64 butterfly dots for h (unchanged)
        double hs = (double)pl * al;
        #pragma unroll
        for (int off = 32; off > 0; off >>= 1) hs += __shfl_xor(hs, off, 64);
        double hd = (double)dl * bl;
        #pragma unroll
        for (int off = 32; off > 0; off >>= 1) hd += __shfl_xor(hd, off, 64);
        if (lane == 0) { h_src[i] = hs; h_dst[i] = hd; }

        // wv row: readlane broadcast + 4 independent FMA chains (same order
        // as previous round -> bit-identical result)
        float a0 = 0.f, a1 = 0.f, a2 = 0.f, a3 = 0.f;
        #pragma unroll
        for (int d = 0; d < DIM; d += 4) {
            a0 += w[d + 0] * lane_bc(pl, d + 0);
            a1 += w[d + 1] * lane_bc(pl, d + 1);
            a2 += w[d + 2] * lane_bc(pl, d + 2);
            a3 += w[d + 3] * lane_bc(pl, d + 3);
        }
        wv_out[(size_t)i * DIM + lane] = (a0 + a1) + (a2 + a3);
    }
}

// ---------------------------------------------------------------------------
// CSR step 1: histogram of dst + per-edge rank (coalesced 4B write).
// ---------------------------------------------------------------------------
__global__ __launch_bounds__(256) void hist_kernel(
    const int* __restrict__ dst, int* __restrict__ cnt,
    int* __restrict__ rank) {
    int e = blockIdx.x * 256 + threadIdx.x;
    if (e >= N_EDGES) return;
    rank[e] = atomicAdd(&cnt[dst[e]], 1);
}

// CSR step 2a: per-block exclusive scan (Hillis-Steele in LDS).
__global__ __launch_bounds__(SCAN_BLK) void scan1_kernel(
    const int* __restrict__ cnt, int* __restrict__ row,
    int* __restrict__ bsum) {
    __shared__ int sh[SCAN_BLK];
    int tid = threadIdx.x;
    int i = blockIdx.x * SCAN_BLK + tid;
    int v = (i < N_NODES) ? cnt[i] : 0;
    sh[tid] = v;
    __syncthreads();
    for (int off = 1; off < SCAN_BLK; off <<= 1) {
        int t = (tid >= off) ? sh[tid - off] : 0;
        __syncthreads();
        sh[tid] += t;
        __syncthreads();
    }
    if (i < N_NODES) row[i] = sh[tid] - v;   // exclusive
    if (tid == SCAN_BLK - 1) bsum[blockIdx.x] = sh[tid];
}

// CSR step 2b: add block-sum prefix (redundant tiny scan per block).
__global__ __launch_bounds__(256) void scan23_kernel(
    int* __restrict__ row, const int* __restrict__ bsum) {
    __shared__ int pref[N_SCAN_BLKS];
    int tid = threadIdx.x;
    if (tid == 0) {
        int run = 0;
        #pragma unroll 8
        for (int k = 0; k < N_SCAN_BLKS; ++k) { pref[k] = run; run += bsum[k]; }
    }
    __syncthreads();
    int i = blockIdx.x * 256 + tid;
    if (i >= N_NODES) return;
    row[i] += pref[i / SCAN_BLK];
}

// CSR step 3: atomic-free scatter of src ids.
__global__ __launch_bounds__(256) void build_kernel(
    const int* __restrict__ src, const int* __restrict__ dst,
    const int* __restrict__ row, const int* __restrict__ rank,
    int* __restrict__ csr_src) {
    int e = blockIdx.x * 256 + threadIdx.x;
    if (e >= N_EDGES) return;
    int pos = row[dst[e]] + rank[e];
    csr_src[pos] = src[e];
}

// ---------------------------------------------------------------------------
// Gather: one wave per dst node (unchanged).
// ---------------------------------------------------------------------------
__global__ __launch_bounds__(256) void node_gather(
    const int* __restrict__ row, const int* __restrict__ cnt,
    const int* __restrict__ csr_src,
    const double* __restrict__ h_src, const double* __restrict__ h_dst,
    const float* __restrict__ wv, float* __restrict__ out) {
    int gtid = blockIdx.x * 256 + threadIdx.x;
    int node = gtid >> 6;
    int lane = threadIdx.x & 63;
    if (node >= N_NODES) return;

    int start = row[node];
    int deg = cnt[node];
    double hd = h_dst[node];

    if (deg <= 64) {
        int s0 = 0;
        double c0 = 0.0;
        if (lane < deg) {
            s0 = csr_src[start + lane];
            c0 = h_src[s0] + hd;
        }
        double r = c0;
        #pragma unroll
        for (int off = 32; off > 0; off >>= 1) r += __shfl_xor(r, off, 64);
        double inv = 1.0 / r;
        float cf0 = (lane < deg) ? (float)(c0 * inv) : 0.f;

        int g = lane >> 4;        // edge-in-quad (0..3)
        int q = lane & 15;        // float4 index within row
        int tmax = (deg + 3) >> 2;
        float ax = 0.f, ay = 0.f, az = 0.f, aw = 0.f;
        for (int t = 0; t < tmax; ++t) {
            int idx = 4 * t + g;
            int s = __shfl(s0, idx, 64);
            float cf = __shfl(cf0, idx, 64);
            const float4* rowp = (const float4*)(wv + (size_t)s * DIM);
            float4 w = rowp[q];
            ax += w.x * cf;
            ay += w.y * cf;
            az += w.z * cf;
            aw += w.w * cf;
        }
        ax += __shfl_xor(ax, 16, 64);
        ay += __shfl_xor(ay, 16, 64);
        az += __shfl_xor(az, 16, 64);
        aw += __shfl_xor(aw, 16, 64);
        ax += __shfl_xor(ax, 32, 64);
        ay += __shfl_xor(ay, 32, 64);
        az += __shfl_xor(az, 32, 64);
        aw += __shfl_xor(aw, 32, 64);
        if (lane < 16) {
            float4 st; st.x = ax; st.y = ay; st.z = az; st.w = aw;
            ((float4*)(out + (size_t)node * DIM))[q] = st;
        }
    } else {
        double denom = 0.0;
        for (int base = 0; base < deg; base += 64) {
            int m = deg - base; if (m > 64) m = 64;
            double c = 0.0;
            if (lane < m) {
                int s = csr_src[start + base + lane];
                c = h_src[s] + hd;
            }
            #pragma unroll
            for (int off = 32; off > 0; off >>= 1) c += __shfl_xor(c, off, 64);
            denom += c;
        }
        double inv = 1.0 / denom;
        float acc = 0.f;
        for (int base = 0; base < deg; base += 64) {
            int m = deg - base; if (m > 64) m = 64;
            int s1 = 0; float cf1 = 0.f;
            if (lane < m) {
                s1 = csr_src[start + base + lane];
                cf1 = (float)((h_src[s1] + hd) * inv);
            }
            for (int j = 0; j < m; ++j) {
                int s = __shfl(s1, j, 64);
                float cf = __shfl(cf1, j, 64);
                acc += wv[(size_t)s * DIM + lane] * cf;
            }
        }
        out[(size_t)node * DIM + lane] = acc;
    }
}

// ---------------------------------------------------------------------------
// Launch
// ---------------------------------------------------------------------------
extern "C" void kernel_launch(void* const* d_in, const int* in_sizes, int n_in,
                              void* d_out, int out_size, void* d_ws, size_t ws_size,
                              hipStream_t stream) {
    const float* d_u = (const float*)d_in[0];
    const float* p_u = (const float*)d_in[1];
    const float* w_q = (const float*)d_in[2];
    const float* w_k = (const float*)d_in[3];
    const float* w_v = (const float*)d_in[4];
    const float* e1  = (const float*)d_in[5];
    const float* e2  = (const float*)d_in[6];
    const int*   src = (const int*)d_in[7];
    const int*   dst = (const int*)d_in[8];
    float* out = (float*)d_out;

    // Workspace: doubles first (8B aligned), then floats, then ints.
    double* a      = (double*)d_ws;
    double* b      = a + DIM;
    double* h_src  = b + DIM;
    double* h_dst  = h_src + N_NODES;
    float*  wv     = (float*)(h_dst + N_NODES);       // N_NODES*DIM floats
    int*    cnt    = (int*)(wv + (size_t)N_NODES * DIM);
    int*    row    = cnt + N_NODES;
    int*    bsum   = row + N_NODES;                   // 128 ints
    int*    rank   = bsum + 128;                      // N_EDGES ints
    int*    csr_src= rank + N_EDGES;                  // N_EDGES ints

    vec_precompute<<<1, 128, 0, stream>>>(w_q, w_k, e1, e2, a, b);

    hipMemsetAsync(cnt, 0, sizeof(int) * N_NODES, stream);

    hist_kernel<<<(N_EDGES + 255) / 256, 256, 0, stream>>>(dst, cnt, rank);

    // wave-per-node fused precompute: 1024 blocks x 4 waves, grid-strided
    node_wave<<<1024, 256, 0, stream>>>(
        d_u, p_u, w_v, a, b, h_src, h_dst, wv);

    scan1_kernel<<<N_SCAN_BLKS, SCAN_BLK, 0, stream>>>(cnt, row, bsum);
    scan23_kernel<<<(N_NODES + 255) / 256, 256, 0, stream>>>(row, bsum);

    build_kernel<<<(N_EDGES + 255) / 256, 256, 0, stream>>>(
        src, dst, row, rank, csr_src);

    node_gather<<<(N_NODES * 64 + 255) / 256, 256, 0, stream>>>(
        row, cnt, csr_src, h_src, h_dst, wv, out);
}